// Round 3
// baseline (161.718 us; speedup 1.0000x reference)
//
#include <hip/hip_runtime.h>

// VectorQuantizer R9: input (16,64,64,64) f32 channel-first, codebook (1024,64) f32.
// out = [quantized (16,64,64,64) f32 | indices (16,64,64) as f32].
//
// A = codebook, B = tokens, mfma_f32_32x32x16_f16, 2-PASS "exact-A x hi-B"
// (math verified R8: absmax 0): A = -2*C split hi+lo (exact to 2^-22); B = f16(x).
// err = |2c.x_lo|, rms ~2.6e-3; EPS=0.04 >= 2*maxerr; flagged tokens (~0.6%)
// resolved by exact fp32 rescan.
//
// R9 structure (from R6/R7/R8 counter triangulation: latency-bound, pipes <23%,
// occupancy & MFMA-count changes null):
//  - 128 tokens/block, 4 accs/wave: 9 A-loads feed 36 MFMAs in 4 independent
//    9-deep chains (was 2x13). Grid 512, fully resident at 2 blk/CU.
//  - explicit ping-pong A-register prefetch (tile t+1 loads issued before tile
//    t's MFMAs) -> L2 latency structurally hidden.
//  - WAVE-parallel exact rescan (R8's block-cooperative serial rescan caused
//    +18us real-data tail and a 40ms poisoned-input outlier): one flagged token
//    per wave, 16 codewords/lane, ~1us/token, no barriers.
//  - esq folded into vq_prep kc==8 lanes (grid 72).
// Tracking: value+slot separate regs -> exact gap test; ties (gap 0) flagged.

typedef _Float16 v8h  __attribute__((ext_vector_type(8)));
typedef float    v16f __attribute__((ext_vector_type(16)));

constexpr int   D         = 64;
constexpr int   K         = 1024;
constexpr int   HW        = 4096;
constexpr int   DHW       = D * HW;
constexpr int   OUT_ELEMS = 16 * DHW;
constexpr float EPS       = 0.04f;

// CH: 32 tiles x 9 chunks x 64 lanes x 8 f16 = 288 KB.
// frag f = t*9+kc; CH[f*512 + lane*8 + j]:
//   kc 0-3: hi of -2*C[row = t*32+(lane&31)][k = kc*16+(lane>>5)*8+j]
//   kc 4-7: lo of same
//   kc 8  : lh==0: j0=e_hi, j1=e_lo (pairs with B5 = ones at k=0,1)

__global__ __launch_bounds__(256) void vq_prep(
    const float* __restrict__ cb, _Float16* __restrict__ CH, float* __restrict__ esq)
{
    const int gid  = blockIdx.x * 256 + threadIdx.x;   // [0, 18432)
    const int lane = gid & 63;
    const int fid  = gid >> 6;                         // [0, 288)
    const int t    = fid / 9;
    const int kc   = fid - 9 * t;
    const int l31  = lane & 31;
    const int lh   = lane >> 5;
    const int cw   = t * 32 + l31;
    v8h h;
    if (kc < 8) {
        const int  kk = kc & 3;
        const bool lo = kc >= 4;
        const float* src = cb + cw * D + kk * 16 + lh * 8;
        #pragma unroll
        for (int j = 0; j < 8; ++j) {
            const float v = -2.0f * src[j];
            const _Float16 vh = (_Float16)v;
            h[j] = lo ? (_Float16)(v - (float)vh) : vh;
        }
    } else {
        #pragma unroll
        for (int j = 0; j < 8; ++j) h[j] = (_Float16)0.0f;
        if (lh == 0) {
            const float4* c4 = (const float4*)(cb + cw * D);
            float a0 = 0.f, a1 = 0.f, a2 = 0.f, a3 = 0.f;
            #pragma unroll
            for (int j = 0; j < 16; ++j) {
                const float4 c = c4[j];
                a0 = fmaf(c.x, c.x, a0);
                a1 = fmaf(c.y, c.y, a1);
                a2 = fmaf(c.z, c.z, a2);
                a3 = fmaf(c.w, c.w, a3);
            }
            const float e = (a0 + a1) + (a2 + a3);
            const _Float16 ehi = (_Float16)e;
            h[0] = ehi;
            h[1] = (_Float16)(e - (float)ehi);
            esq[cw] = e;                               // exact f32 e_sq for rescan
        }
    }
    *(v8h*)(CH + (size_t)fid * 512 + lane * 8) = h;
}

__global__ __launch_bounds__(256, 2) void vq_scan(
    const float* __restrict__ input,
    const float* __restrict__ codebook,
    const _Float16* __restrict__ CH,
    const float* __restrict__ esq,
    float* __restrict__ out)
{
    // u.bf (B-hi staging, dead after fragment loads) unions u.q (epilogue gather).
    __shared__ union {
        _Float16 bf[4][4][64][8];      // [group][kc][lane][8], 16 KB
        float    q[128][65];           // winner rows for epilogue, 33.3 KB
    } u;
    __shared__ float s_pv[4][128];
    __shared__ float s_p2[4][128];
    __shared__ int   s_pk[4][128];
    __shared__ int   s_idx[128];
    __shared__ int   s_list[128];
    __shared__ int   s_cnt;
    __shared__ float s_xf[4][64];      // per-wave rescan token

    const int tid  = threadIdx.x;
    const int lane = tid & 63;
    const int q    = __builtin_amdgcn_readfirstlane(tid >> 6);  // K-quarter / wave id
    const int lh   = lane >> 5;
    const int tok0 = blockIdx.x * 128;
    const int b    = tok0 >> 12;
    const int hwb  = tok0 & 4095;

    if (tid == 0) s_cnt = 0;

    // ---- cooperative B staging: 128 tokens, hi only ----
    {
        const float* xb = input + (size_t)b * DHW + hwb;
        #pragma unroll
        for (int pass = 0; pass < 8; ++pass) {
            const int d   = pass * 8 + (tid >> 5);
            const int tk4 = (tid & 31) * 4;
            const float4 v = *(const float4*)(xb + (size_t)d * HW + tk4);
            const float vv[4] = {v.x, v.y, v.z, v.w};
            #pragma unroll
            for (int uu = 0; uu < 4; ++uu) {
                const int tk = tk4 + uu;
                u.bf[tk >> 5][d >> 4][((d >> 3) & 1) * 32 + (tk & 31)][d & 7] =
                    (_Float16)vv[uu];
            }
        }
    }
    __syncthreads();

    // ---- B hi fragments from LDS: 4 token groups ----
    v8h bh[4][4];
    #pragma unroll
    for (int g = 0; g < 4; ++g)
        #pragma unroll
        for (int kc = 0; kc < 4; ++kc)
            bh[g][kc] = *(const v8h*)&u.bf[g][kc][lane][0];

    // B5: ones at k=0,1 (pairs with esq chunk)
    v8h b5;
    #pragma unroll
    for (int j = 0; j < 8; ++j) b5[j] = (_Float16)0.0f;
    if (lh == 0) { b5[0] = (_Float16)1.0f; b5[1] = (_Float16)1.0f; }

    v16f Z = {0,0,0,0,0,0,0,0,0,0,0,0,0,0,0,0};
    const float INF = __builtin_huge_valf();
    float bv[4] = {INF, INF, INF, INF};
    float b2[4] = {INF, INF, INF, INF};
    int   sl[4] = {0, 0, 0, 0};

    const v8h* Abase = (const v8h*)CH + lane;

    // ---- hot loop: 8 tiles x 36 MFMA (4 groups x (esq + 4 hh + 4 lh)),
    //      ping-pong A prefetch ----
    v8h ah0[4], al0[4], ae0, ah1[4], al1[4], ae1;

    auto loadA = [&](int t, v8h (&ah)[4], v8h (&al)[4], v8h& ae) {
        const v8h* Ap = Abase + (size_t)((q * 8 + t) * 9) * 64;
        #pragma unroll
        for (int kc = 0; kc < 4; ++kc) {
            ah[kc] = Ap[kc * 64];
            al[kc] = Ap[(kc + 4) * 64];
        }
        ae = Ap[512];
    };

    auto tile = [&](int t, const v8h (&ah)[4], const v8h (&al)[4], const v8h& ae) {
        v16f acc[4];
        #pragma unroll
        for (int g = 0; g < 4; ++g)
            acc[g] = __builtin_amdgcn_mfma_f32_32x32x16_f16(ae, b5, Z, 0, 0, 0);
        #pragma unroll
        for (int kc = 0; kc < 4; ++kc)
            #pragma unroll
            for (int g = 0; g < 4; ++g)
                acc[g] = __builtin_amdgcn_mfma_f32_32x32x16_f16(ah[kc], bh[g][kc], acc[g], 0, 0, 0);
        #pragma unroll
        for (int kc = 0; kc < 4; ++kc)
            #pragma unroll
            for (int g = 0; g < 4; ++g)
                acc[g] = __builtin_amdgcn_mfma_f32_32x32x16_f16(al[kc], bh[g][kc], acc[g], 0, 0, 0);
        // top-2 value + slot (value & slot separate: exact gap test)
        #pragma unroll
        for (int r = 0; r < 16; ++r) {
            const int slot = (t << 4) | r;
            #pragma unroll
            for (int g = 0; g < 4; ++g) {
                const float s = acc[g][r];
                b2[g] = __builtin_amdgcn_fmed3f(s, bv[g], b2[g]);
                if (s < bv[g]) { bv[g] = s; sl[g] = slot; }
            }
        }
    };

    loadA(0, ah0, al0, ae0);
    #pragma unroll 1
    for (int t = 0; t < 8; t += 2) {
        loadA(t + 1, ah1, al1, ae1);        // prefetch while tile t computes
        tile(t, ah0, al0, ae0);
        if (t + 2 < 8) loadA(t + 2, ah0, al0, ae0);
        tile(t + 1, ah1, al1, ae1);
    }

    // ---- cross-half-row merge (lane <-> lane^32), decode cw ----
    #pragma unroll
    for (int g = 0; g < 4; ++g) {
        const float obv = __shfl_xor(bv[g], 32, 64);
        const float ob2 = __shfl_xor(b2[g], 32, 64);
        const int   osl = __shfl_xor(sl[g], 32, 64);
        const bool  oth = obv < bv[g];     // strict: ties keep own; exact ties flagged
        const float B1  = oth ? obv : bv[g];
        const float B2  = fminf(fmaxf(bv[g], obv), fminf(b2[g], ob2));
        const int   wsl = oth ? osl : sl[g];
        const int   wlh = oth ? (lh ^ 1) : lh;
        const int   r   = wsl & 15;
        const int   tt  = wsl >> 4;
        const int   cw  = (q * 8 + tt) * 32 + (r & 3) + 8 * (r >> 2) + 4 * wlh;
        if (lane < 32) {
            s_pv[q][g * 32 + lane] = B1;
            s_p2[q][g * 32 + lane] = B2;
            s_pk[q][g * 32 + lane] = cw;
        }
    }
    __syncthreads();

    // ---- merge 4 quarters per token; flag near-ties into list ----
    if (tid < 128) {
        float B1 = INF, B2 = INF; int CW = 0;
        #pragma unroll
        for (int qq = 0; qq < 4; ++qq) {
            const float pv = s_pv[qq][tid];
            const float p2 = s_p2[qq][tid];
            const int   pk = s_pk[qq][tid];
            if (pv < B1) { B2 = fminf(B1, p2); B1 = pv; CW = pk; }
            else         { B2 = fminf(B2, pv); }
        }
        s_idx[tid] = CW;
        if (B2 - B1 < EPS) {
            const int p = atomicAdd(&s_cnt, 1);
            s_list[p] = tid;
        }
    }
    __syncthreads();

    // ---- exact fp32 rescan, WAVE-parallel (one flagged token per wave) ----
    {
        const int cnt = s_cnt;
        for (int ii = q; ii < cnt; ii += 4) {
            const int tl = s_list[ii];
            // token into per-wave LDS (lane = d); intra-wave dep -> compiler waitcnt
            s_xf[q][lane] = input[(size_t)b * DHW + (size_t)lane * HW + (hwb + tl)];
            float dot[16];
            #pragma unroll
            for (int i = 0; i < 16; ++i) dot[i] = 0.f;
            #pragma unroll 4
            for (int dc = 0; dc < 16; ++dc) {
                const float4 x4 = *(const float4*)&s_xf[q][dc * 4];
                #pragma unroll
                for (int i = 0; i < 16; ++i) {
                    const int k = i * 64 + lane;
                    const float4 c4 = *(const float4*)(codebook + (size_t)k * D + dc * 4);
                    dot[i] = fmaf(x4.x, c4.x, dot[i]);
                    dot[i] = fmaf(x4.y, c4.y, dot[i]);
                    dot[i] = fmaf(x4.z, c4.z, dot[i]);
                    dot[i] = fmaf(x4.w, c4.w, dot[i]);
                }
            }
            float bestv = INF; int bestk = 0x7fffffff;
            #pragma unroll
            for (int i = 0; i < 16; ++i) {          // ascending k per lane: strict <
                const int k = i * 64 + lane;
                const float s = fmaf(-2.0f, dot[i], esq[k]);
                if (s < bestv) { bestv = s; bestk = k; }
            }
            #pragma unroll
            for (int off = 1; off < 64; off <<= 1) {  // lexicographic (val, k) reduce
                const float ov = __shfl_xor(bestv, off, 64);
                const int   ok = __shfl_xor(bestk, off, 64);
                if (ov < bestv || (ov == bestv && ok < bestk)) { bestv = ov; bestk = ok; }
            }
            if (lane == 0) s_idx[tl] = bestk;        // distinct tl per wave: no race
        }
    }
    __syncthreads();

    // ---- epilogue: gather winner rows to LDS (u.q overlays dead u.bf) ----
    {
        const int rs  = tid >> 1;      // 128 rows, 2 threads/row
        const int c   = tid & 1;
        const int idx = s_idx[rs];
        const float4* src = (const float4*)(codebook + (size_t)idx * D + c * 32);
        #pragma unroll
        for (int j = 0; j < 8; ++j) {
            const float4 v = src[j];
            float* dst = &u.q[rs][c * 32 + j * 4];
            dst[0] = v.x; dst[1] = v.y; dst[2] = v.z; dst[3] = v.w;
        }
    }
    __syncthreads();
    {
        float* ob = out + (size_t)b * DHW + hwb;
        #pragma unroll
        for (int pass = 0; pass < 8; ++pass) {
            const int d   = pass * 8 + (tid >> 5);
            const int tk4 = (tid & 31) * 4;
            float4 v;
            v.x = u.q[tk4 + 0][d];
            v.y = u.q[tk4 + 1][d];
            v.z = u.q[tk4 + 2][d];
            v.w = u.q[tk4 + 3][d];
            *(float4*)(ob + (size_t)d * HW + tk4) = v;
        }
        if (tid < 128) out[OUT_ELEMS + tok0 + tid] = (float)s_idx[tid];
    }
}

extern "C" void kernel_launch(void* const* d_in, const int* in_sizes, int n_in,
                              void* d_out, int out_size, void* d_ws, size_t ws_size,
                              hipStream_t stream) {
    const float* input    = (const float*)d_in[0];
    const float* codebook = (const float*)d_in[1];
    float* out            = (float*)d_out;

    _Float16* CH  = (_Float16*)d_ws;                   // 294912 B
    float*    esq = (float*)((char*)d_ws + 294912);    // 4096 B

    vq_prep<<<72, 256, 0, stream>>>(codebook, CH, esq);
    vq_scan<<<512, 256, 0, stream>>>(input, codebook, CH, esq, out);
}

// Round 6
// 146.096 us; speedup vs baseline: 1.1069x; 1.1069x over previous
//
#include <hip/hip_runtime.h>

// VectorQuantizer R10: input (16,64,64,64) f32 channel-first, codebook (1024,64) f32.
// out = [quantized (16,64,64,64) f32 | indices (16,64,64) as f32].
//
// mfma_f32_16x16x32_f16, 2-pass exact-A x hi-B (math verified R8/R9, absmax 0):
//   A = -2*C split hi+lo f16 (exact to 2^-22); B = f16(x) hi only.
//   score = esq(exact f32, init in acc) + A.x_hi; err = |2c.x_lo|; EPS=0.04;
//   flagged (~0.6%) resolved by exact fp32 wave-parallel rescan.
//
// R10 rationale (R6/R7/R9 counter triangulation): MFMA pipe floor 11.7us but
// MfmaUtil 22% -> dependent-MFMA-latency bound (2 chains x depth 13). R9's
// 4-chain fix spilled (allocator picks ~cap/2 = 128 regs; need was ~220).
// 16x16x32 gives 4 chains x depth 4 with acc = 4 VGPR each: working set ~115
// fits 128 -> no spills, 4 waves/EU, full grid resident. esq loaded directly
// into acc via broadcast ds_read_b128 (C/D row = (lane>>4)*4+reg) -> kills
// the ones-column MFMA trick + b5 + Z regs; esq term now exact f32.
// Per-step A ping-pong prefetch hides L2 latency structurally.
//
// CH16: frag f = s*4 + c*2 + p (s = 16-codeword block [0,64), c = K-chunk {0,1},
// p = {0:hi,1:lo}); CH[f*512 + lane*8 + j] = -2*C[s*16+(lane&15)][c*32+(lane>>4)*8+j].
// Fragment maps (family-verified): A row=l&15, k=(l>>4)*8+j; B col=l&15, same k;
// C/D col=l&15, row=(l>>4)*4+reg.

typedef _Float16 v8h __attribute__((ext_vector_type(8)));
typedef float    v4f __attribute__((ext_vector_type(4)));

constexpr int   D         = 64;
constexpr int   K         = 1024;
constexpr int   HW        = 4096;
constexpr int   DHW       = D * HW;
constexpr int   OUT_ELEMS = 16 * DHW;
constexpr float EPS       = 0.04f;

__global__ __launch_bounds__(256) void vq_prep(
    const float* __restrict__ cb, _Float16* __restrict__ CH, float* __restrict__ esq)
{
    const int blk = blockIdx.x, tid = threadIdx.x;
    if (blk < 32) {
        const int gid  = blk * 256 + tid;          // [0, 8192)
        const int lane = gid & 63;
        const int fp   = gid >> 6;                 // [0,128) = s*2 + c
        const int c    = fp & 1;
        const int s    = fp >> 1;
        const float* src = cb + (s * 16 + (lane & 15)) * 64 + c * 32 + (lane >> 4) * 8;
        v8h hi, lo;
        #pragma unroll
        for (int j = 0; j < 8; ++j) {
            const float v = -2.0f * src[j];
            const _Float16 vh = (_Float16)v;
            hi[j] = vh;
            lo[j] = (_Float16)(v - (float)vh);
        }
        *(v8h*)(CH + (size_t)(s * 4 + c * 2 + 0) * 512 + lane * 8) = hi;
        *(v8h*)(CH + (size_t)(s * 4 + c * 2 + 1) * 512 + lane * 8) = lo;
    } else {
        const int cw = (blk - 32) * 256 + tid;     // exact f32 e_sq
        const float4* c4 = (const float4*)(cb + cw * D);
        float a0 = 0.f, a1 = 0.f, a2 = 0.f, a3 = 0.f;
        #pragma unroll
        for (int j = 0; j < 16; ++j) {
            const float4 c = c4[j];
            a0 = fmaf(c.x, c.x, a0);
            a1 = fmaf(c.y, c.y, a1);
            a2 = fmaf(c.z, c.z, a2);
            a3 = fmaf(c.w, c.w, a3);
        }
        esq[cw] = (a0 + a1) + (a2 + a3);
    }
}

__global__ __launch_bounds__(256, 2) void vq_scan(
    const float* __restrict__ input,
    const float* __restrict__ codebook,
    const _Float16* __restrict__ CH,
    const float* __restrict__ esq,
    float* __restrict__ out)
{
    // u.bf (B staging, dead after frag loads) unions u.q (epilogue gather).
    __shared__ alignas(16) union {
        _Float16 bf[4][2][64][8];      // [group][kchunk][lane][8], 8 KB
        float    q[64][65];            // winner rows, 16.6 KB
    } u;
    __shared__ alignas(16) float s_esq[K];   // exact e_sq: acc init + rescan, 4 KB
    __shared__ float s_pv[4][64];
    __shared__ float s_p2[4][64];
    __shared__ int   s_pk[4][64];
    __shared__ int   s_idx[64];
    __shared__ int   s_list[64];
    __shared__ int   s_cnt;
    __shared__ float s_xf[4][64];            // per-wave rescan token

    const int tid  = threadIdx.x;
    const int lane = tid & 63;
    const int q    = __builtin_amdgcn_readfirstlane(tid >> 6);  // K-quarter / wave
    const int sub  = lane >> 4;              // 4-lane subgroup = k-subchunk / C-row block
    const int tok0 = blockIdx.x * 64;
    const int b    = tok0 >> 12;
    const int hwb  = tok0 & 4095;

    if (tid == 0) s_cnt = 0;

    // ---- stage exact e_sq (acc init + rescan) ----
    *(float4*)&s_esq[tid * 4] = *(const float4*)&esq[tid * 4];

    // ---- cooperative B staging: 64 tokens, hi f16 only ----
    {
        const float* xb = input + (size_t)b * DHW + hwb;
        #pragma unroll
        for (int pass = 0; pass < 4; ++pass) {
            const int d   = pass * 16 + (tid >> 4);
            const int tk4 = (tid & 15) * 4;
            const float4 v = *(const float4*)(xb + (size_t)d * HW + tk4);
            const float vv[4] = {v.x, v.y, v.z, v.w};
            #pragma unroll
            for (int uu = 0; uu < 4; ++uu) {
                const int tk = tk4 + uu;
                u.bf[tk >> 4][d >> 5][(tk & 15) | (((d >> 3) & 3) << 4)][d & 7] =
                    (_Float16)vv[uu];
            }
        }
    }
    __syncthreads();

    // ---- B fragments: 4 token groups x 2 K-chunks ----
    v8h bh[4][2];
    #pragma unroll
    for (int g = 0; g < 4; ++g)
        #pragma unroll
        for (int c = 0; c < 2; ++c)
            bh[g][c] = *(const v8h*)&u.bf[g][c][lane][0];

    const float INF = __builtin_huge_valf();
    float bv[4] = {INF, INF, INF, INF};
    float b2[4] = {INF, INF, INF, INF};
    int   sl[4] = {0, 0, 0, 0};

    const v8h* CHv = (const v8h*)CH + lane;

    // ---- hot loop: 16 steps x 16 MFMA (4 chains, depth 4), ping-pong prefetch ----
    v8h A0[4], A1[4];   // [0]=hi c0, [1]=lo c0, [2]=hi c1, [3]=lo c1

    auto loadA = [&](int t, v8h (&A)[4]) {
        const v8h* Ap = CHv + (size_t)(q * 16 + t) * 256;
        A[0] = Ap[0];          // c0 hi
        A[1] = Ap[64];         // c0 lo
        A[2] = Ap[128];        // c1 hi
        A[3] = Ap[192];        // c1 lo
    };

    auto step = [&](int t, const v8h (&A)[4]) {
        const int sB = q * 16 + t;
        const v4f e4 = *(const v4f*)&s_esq[sB * 16 + sub * 4];   // broadcast read
        v4f acc[4];
        #pragma unroll
        for (int g = 0; g < 4; ++g) acc[g] = e4;                  // exact esq init
        #pragma unroll
        for (int g = 0; g < 4; ++g)
            acc[g] = __builtin_amdgcn_mfma_f32_16x16x32_f16(A[0], bh[g][0], acc[g], 0, 0, 0);
        #pragma unroll
        for (int g = 0; g < 4; ++g)
            acc[g] = __builtin_amdgcn_mfma_f32_16x16x32_f16(A[2], bh[g][1], acc[g], 0, 0, 0);
        #pragma unroll
        for (int g = 0; g < 4; ++g)
            acc[g] = __builtin_amdgcn_mfma_f32_16x16x32_f16(A[1], bh[g][0], acc[g], 0, 0, 0);
        #pragma unroll
        for (int g = 0; g < 4; ++g)
            acc[g] = __builtin_amdgcn_mfma_f32_16x16x32_f16(A[3], bh[g][1], acc[g], 0, 0, 0);
        // top-2 value + slot (separate regs: exact gap test)
        #pragma unroll
        for (int j = 0; j < 4; ++j) {
            const int slot = t * 16 + sub * 4 + j;   // codeword within quarter
            #pragma unroll
            for (int g = 0; g < 4; ++g) {
                const float s = acc[g][j];
                b2[g] = __builtin_amdgcn_fmed3f(s, bv[g], b2[g]);
                if (s < bv[g]) { bv[g] = s; sl[g] = slot; }
            }
        }
    };

    loadA(0, A0);
    #pragma unroll 1
    for (int t = 0; t < 16; t += 2) {
        loadA(t + 1, A1);                  // prefetch while step t computes
        step(t, A0);
        if (t + 2 < 16) loadA(t + 2, A0);
        step(t + 1, A1);
    }

    // ---- merge across 4 lane-subgroups (same token, different codeword rows) ----
    #pragma unroll
    for (int g = 0; g < 4; ++g) {
        float B1 = bv[g], B2 = b2[g];
        int   SL = sl[g];
        #pragma unroll
        for (int off = 16; off <= 32; off <<= 1) {
            const float ov  = __shfl_xor(B1, off, 64);
            const float ob2 = __shfl_xor(B2, off, 64);
            const int   osl = __shfl_xor(SL, off, 64);
            const float nB2 = fminf(fmaxf(B1, ov), fminf(B2, ob2));
            if (ov < B1 || (ov == B1 && osl < SL)) { B1 = ov; SL = osl; }
            B2 = nB2;
        }
        if (lane < 16) {
            s_pv[q][g * 16 + lane] = B1;
            s_p2[q][g * 16 + lane] = B2;
            s_pk[q][g * 16 + lane] = q * 256 + SL;   // full codeword
        }
    }
    __syncthreads();

    // ---- merge 4 quarters per token; flag near-ties ----
    if (tid < 64) {
        float B1 = INF, B2 = INF; int CW = 0;
        #pragma unroll
        for (int qq = 0; qq < 4; ++qq) {
            const float pv = s_pv[qq][tid];
            const float p2 = s_p2[qq][tid];
            const int   pk = s_pk[qq][tid];
            if (pv < B1) { B2 = fminf(B1, p2); B1 = pv; CW = pk; }
            else         { B2 = fminf(B2, pv); }
        }
        s_idx[tid] = CW;
        if (B2 - B1 < EPS) {
            const int p = atomicAdd(&s_cnt, 1);
            s_list[p] = tid;
        }
    }
    __syncthreads();

    // ---- exact fp32 rescan, WAVE-parallel (one flagged token per wave) ----
    {
        const int cnt = s_cnt;
        for (int ii = q; ii < cnt; ii += 4) {
            const int tl = s_list[ii];
            s_xf[q][lane] = input[(size_t)b * DHW + (size_t)lane * HW + (hwb + tl)];
            float dot[16];
            #pragma unroll
            for (int i = 0; i < 16; ++i) dot[i] = 0.f;
            #pragma unroll 4
            for (int dc = 0; dc < 16; ++dc) {
                const float4 x4 = *(const float4*)&s_xf[q][dc * 4];
                #pragma unroll
                for (int i = 0; i < 16; ++i) {
                    const int k = i * 64 + lane;
                    const float4 c4 = *(const float4*)(codebook + (size_t)k * D + dc * 4);
                    dot[i] = fmaf(x4.x, c4.x, dot[i]);
                    dot[i] = fmaf(x4.y, c4.y, dot[i]);
                    dot[i] = fmaf(x4.z, c4.z, dot[i]);
                    dot[i] = fmaf(x4.w, c4.w, dot[i]);
                }
            }
            float bestv = INF; int bestk = 0x7fffffff;
            #pragma unroll
            for (int i = 0; i < 16; ++i) {          // ascending k per lane: strict <
                const int k = i * 64 + lane;
                const float s = fmaf(-2.0f, dot[i], s_esq[k]);
                if (s < bestv) { bestv = s; bestk = k; }
            }
            #pragma unroll
            for (int off = 1; off < 64; off <<= 1) {  // lexicographic (val, k) reduce
                const float ov = __shfl_xor(bestv, off, 64);
                const int   ok = __shfl_xor(bestk, off, 64);
                if (ov < bestv || (ov == bestv && ok < bestk)) { bestv = ov; bestk = ok; }
            }
            if (lane == 0) s_idx[tl] = bestk;        // distinct tl per wave: no race
        }
    }
    __syncthreads();

    // ---- epilogue: gather winner rows to LDS (u.q overlays dead u.bf) ----
    {
        const int rs  = tid >> 2;
        const int c   = tid & 3;
        const int idx = s_idx[rs];
        const float4* src = (const float4*)(codebook + (size_t)idx * D + c * 16);
        #pragma unroll
        for (int j = 0; j < 4; ++j) {
            const float4 v = src[j];
            float* dst = &u.q[rs][c * 16 + j * 4];
            dst[0] = v.x; dst[1] = v.y; dst[2] = v.z; dst[3] = v.w;
        }
    }
    __syncthreads();
    {
        float* ob = out + (size_t)b * DHW + hwb;
        #pragma unroll
        for (int pass = 0; pass < 4; ++pass) {
            const int d   = pass * 16 + (tid >> 4);
            const int tk4 = (tid & 15) * 4;
            float4 v;
            v.x = u.q[tk4 + 0][d];
            v.y = u.q[tk4 + 1][d];
            v.z = u.q[tk4 + 2][d];
            v.w = u.q[tk4 + 3][d];
            *(float4*)(ob + (size_t)d * HW + tk4) = v;
        }
        if (tid < 64) out[OUT_ELEMS + tok0 + tid] = (float)s_idx[tid];
    }
}

extern "C" void kernel_launch(void* const* d_in, const int* in_sizes, int n_in,
                              void* d_out, int out_size, void* d_ws, size_t ws_size,
                              hipStream_t stream) {
    const float* input    = (const float*)d_in[0];
    const float* codebook = (const float*)d_in[1];
    float* out            = (float*)d_out;

    _Float16* CH  = (_Float16*)d_ws;                   // 262144 B
    float*    esq = (float*)((char*)d_ws + 262144);    // 4096 B

    vq_prep<<<36, 256, 0, stream>>>(codebook, CH, esq);
    vq_scan<<<1024, 256, 0, stream>>>(input, codebook, CH, esq, out);
}